// Round 1
// baseline (340.950 us; speedup 1.0000x reference)
//
#include <hip/hip_runtime.h>
#include <hip/hip_bf16.h>
#include <math.h>

// ---------------------------------------------------------------------------
// Problem: S=2048, B=32, D=512, K=147
// out = concat(applied [B*D], norm_w [B*S])
// ---------------------------------------------------------------------------

__device__ __forceinline__ float wave_sum(float v) {
    for (int off = 32; off; off >>= 1) v += __shfl_xor(v, off);
    return v;
}
__device__ __forceinline__ float wave_max(float v) {
    for (int off = 32; off; off >>= 1) v = fmaxf(v, __shfl_xor(v, off));
    return v;
}

// Kernel A: attended = state @ W^T + b ; ns = attended / safe_norm(attended)
// grid = B, block = D (512). One thread per output element d.
__global__ __launch_bounds__(512) void attend_norm_kernel(
    const float* __restrict__ state, const float* __restrict__ W,
    const float* __restrict__ bias, float* __restrict__ ns, int B, int D) {
    int b = blockIdx.x;
    int d = threadIdx.x;
    __shared__ __align__(16) float st[512];
    st[d] = state[(size_t)b * D + d];
    __syncthreads();

    const float4* Wrow = (const float4*)(W + (size_t)d * D);
    const float4* sv = (const float4*)st;
    float acc = bias[d];
    for (int k = 0; k < D / 4; ++k) {
        float4 w = Wrow[k];
        float4 s4 = sv[k];
        acc += w.x * s4.x + w.y * s4.y + w.z * s4.z + w.w * s4.w;
    }

    // block reduce sum of squares (8 waves)
    float sq = wave_sum(acc * acc);
    __shared__ float wsum[8];
    int lane = d & 63, wv = d >> 6;
    if (lane == 0) wsum[wv] = sq;
    __syncthreads();
    if (d == 0) {
        float t = 0.f;
        for (int i = 0; i < 8; ++i) t += wsum[i];
        wsum[0] = t;
    }
    __syncthreads();
    float n = sqrtf(wsum[0]);
    if (n == 0.f) n = 1e-10f;
    ns[(size_t)b * D + d] = acc / n;
}

// Kernel B: conv1d(prev, conv_w, same-pad) + conv_b -> relu -> row-normalize
// grid = B, block = 256.
__global__ __launch_bounds__(256) void smooth_prev_kernel(
    const float* __restrict__ prev, const float* __restrict__ cw,
    const float* __restrict__ cb, float* __restrict__ prev_probs,
    int B, int S, int K) {
    int b = blockIdx.x;
    int t = threadIdx.x;
    __shared__ float row[2048];
    __shared__ float adj[2048];
    __shared__ float wk[192];
    __shared__ float red[4];
    for (int s = t; s < S; s += 256) row[s] = prev[(size_t)b * S + s];
    for (int j = t; j < K; j += 256) wk[j] = cw[j];
    __syncthreads();

    float cb0 = cb[0];
    int pad = K / 2;
    float lsum = 0.f;
    for (int s = t; s < S; s += 256) {
        int j0 = max(0, pad - s);
        int j1 = min(K, S + pad - s);
        float y = 0.f;
        for (int j = j0; j < j1; ++j) y += row[s + j - pad] * wk[j];
        y = fmaxf(y + cb0, 0.f);
        adj[s] = y;
        lsum += y;
    }
    lsum = wave_sum(lsum);
    int lane = t & 63, wv = t >> 6;
    if (lane == 0) red[wv] = lsum;
    __syncthreads();
    float total = red[0] + red[1] + red[2] + red[3];
    float inv = 1.f / total;
    for (int s = t; s < S; s += 256) prev_probs[(size_t)b * S + s] = adj[s] * inv;
}

// Kernel C: weights[b,s] = dot(ns[b], e[s,b,:]) / safe_norm(e[s,b,:])
// one wave per (s,b); block = 256 (4 waves); grid = S*B/4.
__global__ __launch_bounds__(256) void cos_weights_kernel(
    const float* __restrict__ e, const float* __restrict__ ns,
    float* __restrict__ weights, int S, int B, int D) {
    int wid = (blockIdx.x * 256 + threadIdx.x) >> 6;
    int lane = threadIdx.x & 63;
    if (wid >= S * B) return;
    int b = wid & (B - 1);   // B is a power of two (32)
    int s = wid >> 5;        // wid / B
    const float4* ev = (const float4*)(e + ((size_t)s * B + b) * D);
    const float4* nv = (const float4*)(ns + (size_t)b * D);
    float dot = 0.f, sq = 0.f;
    for (int k = lane; k < D / 4; k += 64) {
        float4 x = ev[k];
        float4 y = nv[k];
        dot += x.x * y.x + x.y * y.y + x.z * y.z + x.w * y.w;
        sq += x.x * x.x + x.y * x.y + x.z * x.z + x.w * x.w;
    }
    dot = wave_sum(dot);
    sq = wave_sum(sq);
    if (lane == 0) {
        float n = sqrtf(sq);
        if (n == 0.f) n = 1e-10f;
        weights[(size_t)b * S + s] = dot / n;
    }
}

// Kernel D: norm_w[b,s] = prev_probs*exp(w-max) / sum(prev_probs*exp(w-max))
// (softmax Z and prev_probs normalizer cancel exactly in the final ratio)
// grid = B, block = 256.
__global__ __launch_bounds__(256) void softmax_combine_kernel(
    const float* __restrict__ weights, const float* __restrict__ prev_probs,
    float* __restrict__ norm_w, int B, int S) {
    int b = blockIdx.x;
    int t = threadIdx.x;
    int lane = t & 63, wv = t >> 6;
    __shared__ float red[4];
    const float* wrow = weights + (size_t)b * S;
    const float* prow = prev_probs + (size_t)b * S;

    float m = -INFINITY;
    for (int s = t; s < S; s += 256) m = fmaxf(m, wrow[s]);
    m = wave_max(m);
    if (lane == 0) red[wv] = m;
    __syncthreads();
    m = fmaxf(fmaxf(red[0], red[1]), fmaxf(red[2], red[3]));
    __syncthreads();

    float lsum = 0.f;
    for (int s = t; s < S; s += 256) lsum += prow[s] * expf(wrow[s] - m);
    lsum = wave_sum(lsum);
    if (lane == 0) red[wv] = lsum;
    __syncthreads();
    float Z = red[0] + red[1] + red[2] + red[3];
    float inv = 1.f / Z;
    for (int s = t; s < S; s += 256)
        norm_w[(size_t)b * S + s] = prow[s] * expf(wrow[s] - m) * inv;
}

// Kernel E: applied[b,d] += sum_{s in chunk} norm_w[b,s]*e[s,b,d]
// grid = (S/CH, B), block = 128 (each thread owns a float4 of D).
__global__ __launch_bounds__(128) void apply_weights_kernel(
    const float* __restrict__ e, const float* __restrict__ nw,
    float* __restrict__ applied, int S, int B, int D, int CH) {
    int b = blockIdx.y;
    int s0 = blockIdx.x * CH;
    int t = threadIdx.x;  // float4 index into D
    float4 acc = {0.f, 0.f, 0.f, 0.f};
    for (int s = s0; s < s0 + CH; ++s) {
        float wgt = nw[(size_t)b * S + s];
        float4 x = ((const float4*)(e + ((size_t)s * B + b) * D))[t];
        acc.x += wgt * x.x;
        acc.y += wgt * x.y;
        acc.z += wgt * x.z;
        acc.w += wgt * x.w;
    }
    float* out = applied + (size_t)b * D + (size_t)t * 4;
    atomicAdd(out + 0, acc.x);
    atomicAdd(out + 1, acc.y);
    atomicAdd(out + 2, acc.z);
    atomicAdd(out + 3, acc.w);
}

extern "C" void kernel_launch(void* const* d_in, const int* in_sizes, int n_in,
                              void* d_out, int out_size, void* d_ws, size_t ws_size,
                              hipStream_t stream) {
    const float* enc   = (const float*)d_in[0];  // [S,B,D]
    const float* state = (const float*)d_in[1];  // [B,D]
    const float* prev  = (const float*)d_in[2];  // [B,S]
    const float* W     = (const float*)d_in[3];  // [D,D]
    const float* bias  = (const float*)d_in[4];  // [D]
    const float* cw    = (const float*)d_in[5];  // [K]
    const float* cb    = (const float*)d_in[6];  // [1]

    // derive dims (S=2048, B=32, D=512, K=147 for this problem)
    const int S = in_sizes[0] / in_sizes[1];
    const int B = in_sizes[2] / S;
    const int D = in_sizes[1] / B;
    const int K = in_sizes[5];

    float* out     = (float*)d_out;
    float* applied = out;               // B*D
    float* norm_w  = out + (size_t)B * D;  // B*S

    float* ws         = (float*)d_ws;
    float* ns         = ws;                          // B*D
    float* prev_probs = ns + (size_t)B * D;          // B*S
    float* weights    = prev_probs + (size_t)B * S;  // B*S

    hipMemsetAsync(applied, 0, (size_t)B * D * sizeof(float), stream);

    attend_norm_kernel<<<B, D, 0, stream>>>(state, W, bias, ns, B, D);
    smooth_prev_kernel<<<B, 256, 0, stream>>>(prev, cw, cb, prev_probs, B, S, K);
    cos_weights_kernel<<<(S * B) / 4, 256, 0, stream>>>(enc, ns, weights, S, B, D);
    softmax_combine_kernel<<<B, 256, 0, stream>>>(weights, prev_probs, norm_w, B, S);
    const int CH = 16;
    apply_weights_kernel<<<dim3(S / CH, B), 128, 0, stream>>>(enc, norm_w, applied, S, B, D, CH);
}

// Round 2
// 254.584 us; speedup vs baseline: 1.3392x; 1.3392x over previous
//
#include <hip/hip_runtime.h>
#include <hip/hip_bf16.h>
#include <math.h>

// ---------------------------------------------------------------------------
// TimeAttender: S=2048, B=32, D=512, K=147
// out = concat(applied [B*D], norm_w [B*S])
//
// Math note: prev_probs = adj/sum(adj) and softmax Z both cancel in
//   norm_w = (prev_probs * softmax(w)) / sum(prev_probs * softmax(w))
//          = adj * exp(w - m) / sum_s(adj * exp(w - m))
// so we never materialize either normalizer.
// ---------------------------------------------------------------------------

__device__ __forceinline__ float wave_sum(float v) {
    for (int off = 32; off; off >>= 1) v += __shfl_xor(v, off);
    return v;
}
__device__ __forceinline__ float wave_max(float v) {
    for (int off = 32; off; off >>= 1) v = fmaxf(v, __shfl_xor(v, off));
    return v;
}

// A1: attended[b,d] = dot(state[b,:], W[d,:]) + bias[d]
// grid = (D/128, B), block = 128. One thread per output d.
__global__ __launch_bounds__(128) void linear_kernel(
    const float* __restrict__ state, const float* __restrict__ W,
    const float* __restrict__ bias, float* __restrict__ attended, int D) {
    int b = blockIdx.y;
    int d = blockIdx.x * 128 + threadIdx.x;
    __shared__ __align__(16) float st[512];
    // 128 threads load 512 floats as float4
    ((float4*)st)[threadIdx.x] = ((const float4*)(state + (size_t)b * D))[threadIdx.x];
    __syncthreads();

    const float4* Wrow = (const float4*)(W + (size_t)d * D);
    const float4* sv = (const float4*)st;
    float acc = bias[d];
#pragma unroll 8
    for (int k = 0; k < 128; ++k) {
        float4 w = Wrow[k];
        float4 s4 = sv[k];
        acc += w.x * s4.x + w.y * s4.y + w.z * s4.z + w.w * s4.w;
    }
    attended[(size_t)b * D + d] = acc;
}

// A2: ns[b,:] = attended[b,:] / safe_norm(attended[b,:])
// grid = B, block = 512.
__global__ __launch_bounds__(512) void rownorm_kernel(
    const float* __restrict__ attended, float* __restrict__ ns, int D) {
    int b = blockIdx.x;
    int d = threadIdx.x;
    float v = attended[(size_t)b * D + d];
    float sq = wave_sum(v * v);
    __shared__ float red[8];
    int lane = d & 63, wv = d >> 6;
    if (lane == 0) red[wv] = sq;
    __syncthreads();
    float t = red[0] + red[1] + red[2] + red[3] + red[4] + red[5] + red[6] + red[7];
    float n = sqrtf(t);
    if (n == 0.f) n = 1e-10f;
    ns[(size_t)b * D + d] = v / n;
}

// B: adj[b,s] = relu(conv1d_same(prev[b,:], wk)[s] + cb)   (unnormalized)
// grid = (S/256, B), block = 256. LDS halo segment per block.
__global__ __launch_bounds__(256) void conv_relu_kernel(
    const float* __restrict__ prev, const float* __restrict__ cw,
    const float* __restrict__ cb, float* __restrict__ adj, int S, int K) {
    int b = blockIdx.y;
    int s0 = blockIdx.x * 256;
    int t = threadIdx.x;
    int pad = K / 2;
    __shared__ float seg[256 + 192];  // 256 + K-1 = 402 used
    __shared__ float wk[192];
    int seglen = 256 + K - 1;
    for (int i = t; i < seglen; i += 256) {
        int s = s0 - pad + i;
        seg[i] = (s >= 0 && s < S) ? prev[(size_t)b * S + s] : 0.f;
    }
    for (int j = t; j < K; j += 256) wk[j] = cw[j];
    __syncthreads();

    float y = cb[0];
    for (int j = 0; j < K; ++j) y += seg[t + j] * wk[j];
    adj[(size_t)b * S + s0 + t] = fmaxf(y, 0.f);
}

// C: weights[b,s] = dot(ns[b], e[s,b,:]) / safe_norm(e[s,b,:])
// one wave per (s,b); block = 256 (4 waves); grid = S*B/4.
__global__ __launch_bounds__(256) void cos_weights_kernel(
    const float* __restrict__ e, const float* __restrict__ ns,
    float* __restrict__ weights, int S, int B, int D) {
    int wid = (blockIdx.x * 256 + threadIdx.x) >> 6;
    int lane = threadIdx.x & 63;
    int b = wid % B;
    int s = wid / B;
    const float4* ev = (const float4*)(e + ((size_t)s * B + b) * D);
    const float4* nv = (const float4*)(ns + (size_t)b * D);
    float dot = 0.f, sq = 0.f;
#pragma unroll
    for (int k = 0; k < 2; ++k) {
        float4 x = ev[lane + 64 * k];
        float4 y = nv[lane + 64 * k];
        dot += x.x * y.x + x.y * y.y + x.z * y.z + x.w * y.w;
        sq  += x.x * x.x + x.y * x.y + x.z * x.z + x.w * x.w;
    }
    dot = wave_sum(dot);
    sq = wave_sum(sq);
    if (lane == 0) {
        float n = sqrtf(sq);
        if (n == 0.f) n = 1e-10f;
        weights[(size_t)b * S + s] = dot / n;
    }
}

// D: norm_w[b,s] = adj*exp(w-max) / sum_s(adj*exp(w-max))
// grid = B, block = 256.
__global__ __launch_bounds__(256) void softmax_combine_kernel(
    const float* __restrict__ weights, const float* __restrict__ adj,
    float* __restrict__ norm_w, int S) {
    int b = blockIdx.x;
    int t = threadIdx.x;
    int lane = t & 63, wv = t >> 6;
    __shared__ float red[4];
    const float* wrow = weights + (size_t)b * S;
    const float* arow = adj + (size_t)b * S;

    float m = -INFINITY;
    for (int s = t; s < S; s += 256) m = fmaxf(m, wrow[s]);
    m = wave_max(m);
    if (lane == 0) red[wv] = m;
    __syncthreads();
    m = fmaxf(fmaxf(red[0], red[1]), fmaxf(red[2], red[3]));
    __syncthreads();

    float lsum = 0.f;
    for (int s = t; s < S; s += 256) lsum += arow[s] * expf(wrow[s] - m);
    lsum = wave_sum(lsum);
    if (lane == 0) red[wv] = lsum;
    __syncthreads();
    float Z = red[0] + red[1] + red[2] + red[3];
    float inv = 1.f / Z;
    for (int s = t; s < S; s += 256)
        norm_w[(size_t)b * S + s] = arow[s] * expf(wrow[s] - m) * inv;
}

// E1: partial[c][b][d] = sum_{s in chunk c} norm_w[b,s] * e[s,b,d]
// grid = (NC, B), block = 128 (one float4 of D per thread). No atomics.
__global__ __launch_bounds__(128) void apply_partial_kernel(
    const float* __restrict__ e, const float* __restrict__ nw,
    float* __restrict__ partial, int S, int B, int D, int CH) {
    int b = blockIdx.y;
    int c = blockIdx.x;
    int s0 = c * CH;
    int t = threadIdx.x;
    float4 acc = {0.f, 0.f, 0.f, 0.f};
    for (int s = s0; s < s0 + CH; ++s) {
        float wgt = nw[(size_t)b * S + s];
        float4 x = ((const float4*)(e + ((size_t)s * B + b) * D))[t];
        acc.x += wgt * x.x;
        acc.y += wgt * x.y;
        acc.z += wgt * x.z;
        acc.w += wgt * x.w;
    }
    ((float4*)(partial + ((size_t)c * B + b) * D))[t] = acc;
}

// E2: applied[b,d] = sum_c partial[c][b][d]
// grid = B, block = 128 (float4 per thread).
__global__ __launch_bounds__(128) void apply_reduce_kernel(
    const float* __restrict__ partial, float* __restrict__ applied,
    int B, int D, int NC) {
    int b = blockIdx.x;
    int t = threadIdx.x;
    float4 acc = {0.f, 0.f, 0.f, 0.f};
    for (int c = 0; c < NC; ++c) {
        float4 x = ((const float4*)(partial + ((size_t)c * B + b) * D))[t];
        acc.x += x.x; acc.y += x.y; acc.z += x.z; acc.w += x.w;
    }
    ((float4*)(applied + (size_t)b * D))[t] = acc;
}

extern "C" void kernel_launch(void* const* d_in, const int* in_sizes, int n_in,
                              void* d_out, int out_size, void* d_ws, size_t ws_size,
                              hipStream_t stream) {
    const float* enc   = (const float*)d_in[0];  // [S,B,D]
    const float* state = (const float*)d_in[1];  // [B,D]
    const float* prev  = (const float*)d_in[2];  // [B,S]
    const float* W     = (const float*)d_in[3];  // [D,D]
    const float* bias  = (const float*)d_in[4];  // [D]
    const float* cw    = (const float*)d_in[5];  // [K]
    const float* cb    = (const float*)d_in[6];  // [1]

    const int S = in_sizes[0] / in_sizes[1];   // 2048
    const int B = in_sizes[2] / S;             // 32
    const int D = in_sizes[1] / B;             // 512
    const int K = in_sizes[5];                 // 147

    float* out     = (float*)d_out;
    float* applied = out;                    // B*D
    float* norm_w  = out + (size_t)B * D;    // B*S

    const int NC = 32;           // apply chunks
    const int CH = S / NC;       // 64 rows per chunk

    float* ws       = (float*)d_ws;
    float* attended = ws;                            // B*D
    float* ns       = attended + (size_t)B * D;      // B*D
    float* adj      = ns + (size_t)B * D;            // B*S
    float* weights  = adj + (size_t)B * S;           // B*S
    float* partial  = weights + (size_t)B * S;       // NC*B*D

    linear_kernel<<<dim3(D / 128, B), 128, 0, stream>>>(state, W, bias, attended, D);
    conv_relu_kernel<<<dim3(S / 256, B), 256, 0, stream>>>(prev, cw, cb, adj, S, K);
    rownorm_kernel<<<B, D, 0, stream>>>(attended, ns, D);
    cos_weights_kernel<<<(S * B) / 4, 256, 0, stream>>>(enc, ns, weights, S, B, D);
    softmax_combine_kernel<<<B, 256, 0, stream>>>(weights, adj, norm_w, S);
    apply_partial_kernel<<<dim3(NC, B), 128, 0, stream>>>(enc, norm_w, partial, S, B, D, CH);
    apply_reduce_kernel<<<B, 128, 0, stream>>>(partial, applied, B, D, NC);
}

// Round 3
// 252.257 us; speedup vs baseline: 1.3516x; 1.0092x over previous
//
#include <hip/hip_runtime.h>
#include <hip/hip_bf16.h>
#include <math.h>

// ---------------------------------------------------------------------------
// TimeAttender: S=2048, B=32, D=512, K=147
// out = concat(applied [B*D], norm_w [B*S])
//
// Math notes:
//  * prev_probs normalizer and softmax Z cancel in
//      norm_w = adj * exp(w) / sum_s(adj * exp(w))
//  * w is a cosine similarity in [-1,1] -> exp(w) in [0.37, 2.72]:
//    max-subtraction is unnecessary for fp32 safety, so the apply pass can
//    run single-pass (flash-style): e is read from HBM exactly ONCE.
// ---------------------------------------------------------------------------

__device__ __forceinline__ float wave_sum(float v) {
    for (int off = 32; off; off >>= 1) v += __shfl_xor(v, off);
    return v;
}

// ---------------------------------------------------------------------------
// K1: grid (2 + S/256, B), block 256. Role split on blockIdx.x:
//   bx < 2      : attended[b, bx*256+t] = dot(state[b,:], W[d,:]) + bias[d]
//   bx >= 2     : adj[b, s] = relu(conv1d_same(prev[b,:], cw)[s] + cb0)
// ---------------------------------------------------------------------------
__global__ __launch_bounds__(256) void front_kernel(
    const float* __restrict__ state, const float* __restrict__ W,
    const float* __restrict__ bias, const float* __restrict__ prev,
    const float* __restrict__ cw, const float* __restrict__ cb,
    float* __restrict__ attended, float* __restrict__ adj,
    int S, int D, int K) {
    __shared__ __align__(16) float smem[1024];
    int b = blockIdx.y;
    int t = threadIdx.x;

    if (blockIdx.x < 2) {
        // ---- linear part ----
        if (t < D / 4)
            ((float4*)smem)[t] = ((const float4*)(state + (size_t)b * D))[t];
        __syncthreads();
        int d = blockIdx.x * 256 + t;
        const float4* Wrow = (const float4*)(W + (size_t)d * D);
        const float4* sv = (const float4*)smem;
        float acc = bias[d];
#pragma unroll 8
        for (int k = 0; k < 128; ++k) {
            float4 w4 = Wrow[k];
            float4 s4 = sv[k];
            acc += w4.x * s4.x + w4.y * s4.y + w4.z * s4.z + w4.w * s4.w;
        }
        attended[(size_t)b * D + d] = acc;
    } else {
        // ---- conv part ----
        int s0 = (blockIdx.x - 2) * 256;
        int pad = K / 2;
        int seglen = 256 + K - 1;
        float* seg = smem;            // seglen floats (<= 256+255)
        float* wk = smem + 512;       // K floats (<= 256)
        for (int i = t; i < seglen; i += 256) {
            int s = s0 - pad + i;
            seg[i] = (s >= 0 && s < S) ? prev[(size_t)b * S + s] : 0.f;
        }
        for (int j = t; j < K; j += 256) wk[j] = cw[j];
        __syncthreads();
        float y = cb[0];
        for (int j = 0; j < K; ++j) y += seg[t + j] * wk[j];
        adj[(size_t)b * S + s0 + t] = fmaxf(y, 0.f);
    }
}

// ---------------------------------------------------------------------------
// K2 (main, single e pass): grid (NCB/4, B), block 256 = 4 waves.
// Each WAVE owns chunk c = bx*4+wave of CH consecutive s for batch b:
//   - recompute ns[b,:] slice in registers from attended (2 KB, L2-hot)
//   - per row: w = dot(ns,e_row)/||e_row||; coef = adj*exp(w)
//              acc += coef*row; z += coef; u[b,s] = coef
//   - store acc -> partial[c][b][:], z -> zbuf[c][b]
// ---------------------------------------------------------------------------
__global__ __launch_bounds__(256) void main_kernel(
    const float* __restrict__ e, const float* __restrict__ attended,
    const float* __restrict__ adj, float* __restrict__ partial,
    float* __restrict__ zbuf, float* __restrict__ u,
    int S, int B, int D, int CH) {
    int wave = threadIdx.x >> 6;
    int lane = threadIdx.x & 63;
    int c = blockIdx.x * 4 + wave;
    int b = blockIdx.y;

    // ns slice for this lane (d = lane*4.. and d = 256+lane*4..)
    const float4* att4 = (const float4*)(attended + (size_t)b * D);
    float4 a0 = att4[lane];
    float4 a1 = att4[lane + 64];
    float asq = a0.x * a0.x + a0.y * a0.y + a0.z * a0.z + a0.w * a0.w
              + a1.x * a1.x + a1.y * a1.y + a1.z * a1.z + a1.w * a1.w;
    asq = wave_sum(asq);
    float an = sqrtf(asq);
    if (an == 0.f) an = 1e-10f;
    float ainv = 1.f / an;
    float4 ns0, ns1;
    ns0.x = a0.x * ainv; ns0.y = a0.y * ainv; ns0.z = a0.z * ainv; ns0.w = a0.w * ainv;
    ns1.x = a1.x * ainv; ns1.y = a1.y * ainv; ns1.z = a1.z * ainv; ns1.w = a1.w * ainv;

    float4 acc0 = {0.f, 0.f, 0.f, 0.f};
    float4 acc1 = {0.f, 0.f, 0.f, 0.f};
    float z = 0.f;

    int s0 = c * CH;
    const float4* row4 = (const float4*)(e + ((size_t)s0 * B + b) * D);
    size_t rstride = (size_t)B * D / 4;  // float4 stride between s rows

    float4 x0 = row4[lane];
    float4 x1 = row4[lane + 64];
    for (int i = 0; i < CH; ++i) {
        float4 nx0, nx1;
        if (i + 1 < CH) {
            nx0 = row4[rstride + lane];
            nx1 = row4[rstride + lane + 64];
        }
        float dot = x0.x * ns0.x + x0.y * ns0.y + x0.z * ns0.z + x0.w * ns0.w
                  + x1.x * ns1.x + x1.y * ns1.y + x1.z * ns1.z + x1.w * ns1.w;
        float sq  = x0.x * x0.x + x0.y * x0.y + x0.z * x0.z + x0.w * x0.w
                  + x1.x * x1.x + x1.y * x1.y + x1.z * x1.z + x1.w * x1.w;
        dot = wave_sum(dot);
        sq  = wave_sum(sq);
        float n = sqrtf(sq);
        if (n == 0.f) n = 1e-10f;
        float w = dot / n;
        float coef = adj[(size_t)b * S + s0 + i] * __expf(w);
        if (lane == 0) u[(size_t)b * S + s0 + i] = coef;
        acc0.x += coef * x0.x; acc0.y += coef * x0.y;
        acc0.z += coef * x0.z; acc0.w += coef * x0.w;
        acc1.x += coef * x1.x; acc1.y += coef * x1.y;
        acc1.z += coef * x1.z; acc1.w += coef * x1.w;
        z += coef;
        x0 = nx0; x1 = nx1;
        row4 += rstride;
    }

    float4* p4 = (float4*)(partial + ((size_t)c * B + b) * D);
    p4[lane] = acc0;
    p4[lane + 64] = acc1;
    if (lane == 0) zbuf[(size_t)c * B + b] = z;
}

// ---------------------------------------------------------------------------
// K3: grid B, block 256.
//   Z = sum_c zbuf[c][b];  applied[b,:] = sum_c partial[c][b][:] / Z;
//   norm_w[b,s] = u[b,s] / Z
// ---------------------------------------------------------------------------
__global__ __launch_bounds__(256) void combine_kernel(
    const float* __restrict__ partial, const float* __restrict__ zbuf,
    const float* __restrict__ u, float* __restrict__ applied,
    float* __restrict__ norm_w, int S, int B, int D, int NCB) {
    int b = blockIdx.x;
    int t = threadIdx.x;
    int lane = t & 63, wv = t >> 6;
    __shared__ float red[4];
    __shared__ float zsh;

    // Z reduce (threads 0..NCB-1 load one z each; NCB <= 256)
    float zt = (t < NCB) ? zbuf[(size_t)t * B + b] : 0.f;
    zt = wave_sum(zt);
    if (lane == 0) red[wv] = zt;
    __syncthreads();
    if (t == 0) zsh = 1.f / (red[0] + red[1] + red[2] + red[3]);
    __syncthreads();
    float inv = zsh;

    // applied: threads 0..127 each own one float4 of D
    if (t < D / 4) {
        float4 acc = {0.f, 0.f, 0.f, 0.f};
        const float4* p4 = (const float4*)partial;
        for (int c = 0; c < NCB; ++c) {
            float4 x = p4[((size_t)c * B + b) * (D / 4) + t];
            acc.x += x.x; acc.y += x.y; acc.z += x.z; acc.w += x.w;
        }
        acc.x *= inv; acc.y *= inv; acc.z *= inv; acc.w *= inv;
        ((float4*)(applied + (size_t)b * D))[t] = acc;
    }

    // norm_w
    for (int s = t; s < S; s += 256)
        norm_w[(size_t)b * S + s] = u[(size_t)b * S + s] * inv;
}

extern "C" void kernel_launch(void* const* d_in, const int* in_sizes, int n_in,
                              void* d_out, int out_size, void* d_ws, size_t ws_size,
                              hipStream_t stream) {
    const float* enc   = (const float*)d_in[0];  // [S,B,D]
    const float* state = (const float*)d_in[1];  // [B,D]
    const float* prev  = (const float*)d_in[2];  // [B,S]
    const float* W     = (const float*)d_in[3];  // [D,D]
    const float* bias  = (const float*)d_in[4];  // [D]
    const float* cw    = (const float*)d_in[5];  // [K]
    const float* cb    = (const float*)d_in[6];  // [1]

    const int S = in_sizes[0] / in_sizes[1];   // 2048
    const int B = in_sizes[2] / S;             // 32
    const int D = in_sizes[1] / B;             // 512
    const int K = in_sizes[5];                 // 147

    float* out     = (float*)d_out;
    float* applied = out;                    // B*D
    float* norm_w  = out + (size_t)B * D;    // B*S

    const int NCB = 128;        // chunks per batch row (one wave each)
    const int CH = S / NCB;     // 16 s-rows per chunk

    float* ws       = (float*)d_ws;
    float* attended = ws;                            // B*D
    float* adj      = attended + (size_t)B * D;      // B*S
    float* u        = adj + (size_t)B * S;           // B*S
    float* zbuf     = u + (size_t)B * S;             // NCB*B
    float* partial  = zbuf + (size_t)NCB * B;        // NCB*B*D

    front_kernel<<<dim3(2 + S / 256, B), 256, 0, stream>>>(
        state, W, bias, prev, cw, cb, attended, adj, S, D, K);
    main_kernel<<<dim3(NCB / 4, B), 256, 0, stream>>>(
        enc, attended, adj, partial, zbuf, u, S, B, D, CH);
    combine_kernel<<<B, 256, 0, stream>>>(
        partial, zbuf, u, applied, norm_w, S, B, D, NCB);
}